// Round 2
// baseline (192.974 us; speedup 1.0000x reference)
//
#include <hip/hip_runtime.h>
#include <stdint.h>

#define NL     8192
#define NH     32768
#define FDIM   128
#define KSEL   32
#define CHUNK  1024
#define NCHUNK (NL / CHUNK)
#define QPW    8                 // queries per wave
#define NWAVES 4
#define BLOCK  (NWAVES * 64)
#define QPB    (NWAVES * QPW)    // 32 queries per block
#define BUFCAP 128

__device__ __forceinline__ int imin(int a, int b) { return a < b ? a : b; }
__device__ __forceinline__ int imax(int a, int b) { return a > b ? a : b; }

__global__ __launch_bounds__(BLOCK, 4)
void knn_interp_kernel(const float* __restrict__ x,
                       const float* __restrict__ pos_l,
                       const float* __restrict__ pos_h,
                       float* __restrict__ out)
{
    __shared__ float4   s_cand[CHUNK];          // 16 KB staged (px,py,pz,|l|^2)
    __shared__ uint16_t s_idx[QPB][BUFCAP];     // 8 KB candidate index buffers
    __shared__ uint32_t s_cnt[QPB];
    __shared__ float    s_wd2[QPB][KSEL];       // 4 KB winner d2 (fp32 from fp64)
    __shared__ uint16_t s_widx[QPB][KSEL];      // 2 KB winner indices

    const int tid   = threadIdx.x;
    const int lane  = tid & 63;
    const int wid   = tid >> 6;
    const int qbase = blockIdx.x * QPB + wid * QPW;

    // wave-uniform per-query params (expansion form for the fast sweeps)
    float hx2[QPW], hy2[QPW], hz2[QPW], h2c[QPW];
#pragma unroll
    for (int q = 0; q < QPW; ++q) {
        const float ax = pos_h[(qbase + q) * 3 + 0];
        const float ay = pos_h[(qbase + q) * 3 + 1];
        const float az = pos_h[(qbase + q) * 3 + 2];
        hx2[q] = -2.0f * ax; hy2[q] = -2.0f * ay; hz2[q] = -2.0f * az;
        h2c[q] = ax * ax + ay * ay + az * az;
    }

    float rmin[QPW];
#pragma unroll
    for (int q = 0; q < QPW; ++q) rmin[q] = INFINITY;

    // ---------------- Sweep A: per-lane min d2 per query ----------------
    for (int c = 0; c < NCHUNK; ++c) {
        __syncthreads();
        for (int i = tid; i < CHUNK; i += BLOCK) {
            const int g = c * CHUNK + i;
            const float px = pos_l[g * 3 + 0];
            const float py = pos_l[g * 3 + 1];
            const float pz = pos_l[g * 3 + 2];
            s_cand[i] = make_float4(px, py, pz, px * px + py * py + pz * pz);
        }
        __syncthreads();
#pragma unroll 4
        for (int i = 0; i < CHUNK / 64; ++i) {
            const float4 p = s_cand[i * 64 + lane];
#pragma unroll
            for (int q = 0; q < QPW; ++q) {
                float d2 = fmaf(hx2[q], p.x, p.w);
                d2 = fmaf(hy2[q], p.y, d2);
                d2 = fmaf(hz2[q], p.z, d2);
                d2 = d2 + h2c[q];
                rmin[q] = fminf(rmin[q], d2);
            }
        }
    }

    // --- tau = 32nd smallest of the 64 lane minima (bitonic, fp32) ---
    float tau_acc[QPW];
#pragma unroll
    for (int q = 0; q < QPW; ++q) {
        float v = rmin[q];
#pragma unroll
        for (int k = 2; k <= 64; k <<= 1) {
#pragma unroll
            for (int j = k >> 1; j >= 1; j >>= 1) {
                const float o     = __shfl_xor(v, j);
                const bool  up    = ((lane & k) == 0);
                const bool  lower = ((lane & j) == 0);
                v = (lower == up) ? fminf(v, o) : fmaxf(v, o);
            }
        }
        const float tau = __shfl(v, 31);
        // margin covers expansion-form fp32 rounding (~3e-6 abs) and
        // expansion-vs-direct-f64 discrepancy for the final exact re-rank
        tau_acc[q] = tau + 1e-4f;
    }

    if (tid < QPB) s_cnt[tid] = 0;

    // ---------------- Sweep B: collect candidate indices <= tau ----------------
    for (int c = 0; c < NCHUNK; ++c) {
        __syncthreads();   // also publishes the counter reset on first iter
        for (int i = tid; i < CHUNK; i += BLOCK) {
            const int g = c * CHUNK + i;
            const float px = pos_l[g * 3 + 0];
            const float py = pos_l[g * 3 + 1];
            const float pz = pos_l[g * 3 + 2];
            s_cand[i] = make_float4(px, py, pz, px * px + py * py + pz * pz);
        }
        __syncthreads();
#pragma unroll 2
        for (int i = 0; i < CHUNK / 64; ++i) {
            const int ci = i * 64 + lane;
            const float4 p = s_cand[ci];
#pragma unroll
            for (int q = 0; q < QPW; ++q) {
                float d2 = fmaf(hx2[q], p.x, p.w);
                d2 = fmaf(hy2[q], p.y, d2);
                d2 = fmaf(hz2[q], p.z, d2);
                d2 = d2 + h2c[q];
                if (d2 <= tau_acc[q]) {
                    const uint32_t pos = atomicAdd(&s_cnt[wid * QPW + q], 1u);
                    if (pos < BUFCAP) s_idx[wid * QPW + q][pos] = (uint16_t)(c * CHUNK + ci);
                }
            }
        }
    }

    // ---- Final: exact fp64 re-rank of buffered candidates, pick top-32 ----
    // (s_cnt/s_idx/s_wd2/s_widx for query qq are private to wave wid; LDS ops
    //  within a wave are ordered, so no barrier is needed here.)
#pragma unroll 1
    for (int q = 0; q < QPW; ++q) {
        const int qq = wid * QPW + q;
        uint32_t M = s_cnt[qq];
        if (M > BUFCAP) M = BUFCAP;   // astronomically unlikely overflow

        const double axd = (double)(-0.5f * hx2[q]);
        const double ayd = (double)(-0.5f * hy2[q]);
        const double azd = (double)(-0.5f * hz2[q]);

        const int i0 = ((uint32_t)(2 * lane)     < M) ? (int)s_idx[qq][2 * lane]     : -1;
        const int i1 = ((uint32_t)(2 * lane + 1) < M) ? (int)s_idx[qq][2 * lane + 1] : -1;
        float f0 = INFINITY, f1 = INFINITY;
        if (i0 >= 0) {
            const double dx = (double)pos_l[i0 * 3 + 0] - axd;
            const double dy = (double)pos_l[i0 * 3 + 1] - ayd;
            const double dz = (double)pos_l[i0 * 3 + 2] - azd;
            f0 = (float)(dx * dx + dy * dy + dz * dz);
        }
        if (i1 >= 0) {
            const double dx = (double)pos_l[i1 * 3 + 0] - axd;
            const double dy = (double)pos_l[i1 * 3 + 1] - ayd;
            const double dz = (double)pos_l[i1 * 3 + 2] - azd;
            f1 = (float)(dx * dx + dy * dy + dz * dz);
        }

        // bitonic-128 sort of d2 keys (int bits; d2 >= 0 so int order = float order)
        int v0 = __float_as_int(f0);
        int v1 = __float_as_int(f1);
#pragma unroll
        for (int k = 2; k <= 128; k <<= 1) {
            const bool up = ((lane & (k >> 1)) == 0);
#pragma unroll
            for (int j = k >> 1; j >= 2; j >>= 1) {
                const int  xo    = j >> 1;
                const bool lower = ((lane & xo) == 0);
                const int o0 = __shfl_xor(v0, xo);
                const int o1 = __shfl_xor(v1, xo);
                v0 = (lower == up) ? imin(v0, o0) : imax(v0, o0);
                v1 = (lower == up) ? imin(v1, o1) : imax(v1, o1);
            }
            const int mn = imin(v0, v1), mx = imax(v0, v1);  // j == 1 (in-lane)
            v0 = up ? mn : mx;
            v1 = up ? mx : mn;
        }
        // rank-31 element (32nd smallest) lives at element 31 = lane 15, slot v1
        const int tau32 = __shfl(v1, 15);

        // compact the winners (<= tau32) into s_wd2/s_widx via ballot prefix
        const bool a0 = (i0 >= 0) && (__float_as_int(f0) <= tau32);
        const bool a1 = (i1 >= 0) && (__float_as_int(f1) <= tau32);
        const unsigned long long b0 = __ballot(a0);
        const unsigned long long b1 = __ballot(a1);
        const unsigned long long mb = (lane == 63) ? 0x7FFFFFFFFFFFFFFFull
                                                   : ((1ull << (lane + 1)) - 1ull) >> 1;
        // mb = bits strictly below `lane`
        const int base = __popcll(b0 & mb) + __popcll(b1 & mb);
        const int p0 = base;
        const int p1 = base + (a0 ? 1 : 0);
        if (a0 && p0 < KSEL) { s_wd2[qq][p0] = f0; s_widx[qq][p0] = (uint16_t)i0; }
        if (a1 && p1 < KSEL) { s_wd2[qq][p1] = f1; s_widx[qq][p1] = (uint16_t)i1; }
    }

    // ---------------- gather + inverse-d2 weighted average ----------------
#pragma unroll 1
    for (int q = 0; q < QPW; ++q) {
        const int qq = wid * QPW + q;
        const int gq = qbase + q;
        float acc0 = 0.0f, acc1 = 0.0f, wsum = 0.0f;
#pragma unroll 8
        for (int kk = 0; kk < KSEL; ++kk) {
            const float d2  = s_wd2[qq][kk];
            const float w   = 1.0f / fmaxf(d2, 1e-16f);
            const int   idx = (int)s_widx[qq][kk];
            const float* row = x + (size_t)idx * FDIM;
            acc0 = fmaf(w, row[lane], acc0);
            acc1 = fmaf(w, row[lane + 64], acc1);
            wsum += w;
        }
        const float invw = 1.0f / wsum;
        out[(size_t)gq * FDIM + lane]      = acc0 * invw;
        out[(size_t)gq * FDIM + 64 + lane] = acc1 * invw;
    }
}

extern "C" void kernel_launch(void* const* d_in, const int* in_sizes, int n_in,
                              void* d_out, int out_size, void* d_ws, size_t ws_size,
                              hipStream_t stream) {
    const float* x     = (const float*)d_in[0];
    const float* pos_l = (const float*)d_in[1];
    const float* pos_h = (const float*)d_in[2];
    float* out = (float*)d_out;
    dim3 grid(NH / QPB);
    dim3 block(BLOCK);
    hipLaunchKernelGGL(knn_interp_kernel, grid, block, 0, stream,
                       x, pos_l, pos_h, out);
}